// Round 1
// baseline (165.751 us; speedup 1.0000x reference)
//
#include <hip/hip_runtime.h>

#define BB 4
#define NN 2048
#define DD 256
#define NTILES (NN / 64)   // 32 n-tiles of 64

// Kernel 1: rnorm[row] = 1/||features[row,:]|| for row in [0, B*N).
// One wave per row; lane l holds float4 at elements [4l,4l+4).
// Also zero-inits the global accumulators (ws is poisoned 0xAA).
__global__ __launch_bounds__(256) void rnorm_kernel(const float* __restrict__ feat,
                                                    float* __restrict__ rnorm,
                                                    float* gsum, unsigned int* gcnt) {
    if (blockIdx.x == 0 && threadIdx.x < 2) {
        if (threadIdx.x == 0) *gsum = 0.0f;
        else                  *gcnt = 0u;
    }
    const int wave = threadIdx.x >> 6;
    const int lane = threadIdx.x & 63;
    const int row  = blockIdx.x * 4 + wave;              // 0..8191
    const float4 v = ((const float4*)(feat + (size_t)row * DD))[lane];
    float s = v.x * v.x + v.y * v.y + v.z * v.z + v.w * v.w;
#pragma unroll
    for (int off = 32; off >= 1; off >>= 1) s += __shfl_xor(s, off, 64);
    if (lane == 0) {
        float rn = rsqrtf(s);
        rn = rn * (1.5f - 0.5f * s * rn * rn);           // one Newton step
        rnorm[row] = rn;
    }
}

// Kernel 2: block = (pair i*B+j, tile of 64 n). Stage denormed pd[i,j,:,:] in
// LDS; each wave handles 16 n, scanning all 2048 m in 64-wide chunks.
// Sparse hits (~6.5e-4 density) -> wave-cooperative 256-dot per match.
__global__ __launch_bounds__(256) void scan_kernel(const float* __restrict__ feat,
                                                   const float* __restrict__ pts_src,
                                                   const float* __restrict__ pts_dst,
                                                   const float* __restrict__ rnorm,
                                                   const int* __restrict__ hptr,
                                                   const int* __restrict__ wptr,
                                                   float* gsum, unsigned int* gcnt) {
    __shared__ float2 spd[NN];                           // denormed dst points, 16 KB
    const int pair = blockIdx.x >> 5;                    // / NTILES
    const int tile = blockIdx.x & 31;
    const int i = pair >> 2;
    const int j = pair & 3;
    const float sx = ((float)(*wptr) - 1.0f) * 0.5f;
    const float sy = ((float)(*hptr) - 1.0f) * 0.5f;

    {   // cooperative staging: 2048 float2 = 1024 float4
        const float4* src = (const float4*)(pts_dst + (size_t)(i * BB + j) * NN * 2);
        float4* dst = (float4*)spd;
        for (int t = threadIdx.x; t < NN / 2; t += 256) {
            float4 v = src[t];
            v.x = (v.x + 1.0f) * sx;  v.y = (v.y + 1.0f) * sy;
            v.z = (v.z + 1.0f) * sx;  v.w = (v.w + 1.0f) * sy;
            dst[t] = v;
        }
    }
    __syncthreads();

    const int wave = threadIdx.x >> 6;
    const int lane = threadIdx.x & 63;
    float lsum = 0.0f;
    unsigned int lcnt = 0u;

    for (int k = 0; k < 16; ++k) {
        const int n = tile * 64 + wave * 16 + k;
        const float psx = (pts_src[(size_t)(i * NN + n) * 2 + 0] + 1.0f) * sx;
        const float psy = (pts_src[(size_t)(i * NN + n) * 2 + 1] + 1.0f) * sy;
        // this wave's fragment of features[j,n,:]
        const float4 fa = ((const float4*)(feat + (size_t)(j * NN + n) * DD))[lane];
        const float rna = rnorm[j * NN + n];

        for (int c = 0; c < NN / 64; ++c) {
            const int m = c * 64 + lane;
            const float2 q = spd[m];
            const float dx = psx - q.x;
            const float dy = psy - q.y;
            const float d2 = dx * dx + dy * dy;
            unsigned long long mk = __ballot(d2 <= 64.0f);
            while (mk) {                                 // wave-uniform sparse hits
                const int b = __ffsll(mk) - 1;
                mk &= mk - 1;
                const int mm = c * 64 + b;
                const float4 fb = ((const float4*)(feat + (size_t)(i * NN + mm) * DD))[lane];
                float d = fa.x * fb.x + fa.y * fb.y + fa.z * fb.z + fa.w * fb.w;
#pragma unroll
                for (int off = 32; off >= 1; off >>= 1) d += __shfl_xor(d, off, 64);
                const float cosv = d * rna * rnorm[i * NN + mm];
                lsum += 1.0f - cosv;                     // uniform across lanes
                lcnt++;
            }
        }
    }
    if (lane == 0) {
        atomicAdd(gsum, lsum);
        atomicAdd(gcnt, lcnt);
    }
}

__global__ void finalize_kernel(const float* gsum, const unsigned int* gcnt,
                                float* out) {
    if (threadIdx.x == 0 && blockIdx.x == 0) {
        const unsigned int c = *gcnt;
        const float denom = (c > 0u) ? (float)c : 1.0f;  // max(cnt, 1)
        out[0] = *gsum / denom;
    }
}

extern "C" void kernel_launch(void* const* d_in, const int* in_sizes, int n_in,
                              void* d_out, int out_size, void* d_ws, size_t ws_size,
                              hipStream_t stream) {
    const float* feat    = (const float*)d_in[0];   // [B,N,D] f32
    const float* pts_src = (const float*)d_in[1];   // [B,N,2] f32
    const float* pts_dst = (const float*)d_in[2];   // [B,B,N,2] f32
    // d_in[3] = invis_idx [3,128] int32 — unused by the reference
    const int* hptr = (const int*)d_in[4];          // height (scalar)
    const int* wptr = (const int*)d_in[5];          // width  (scalar)
    float* out = (float*)d_out;

    float*        gsum  = (float*)d_ws;
    unsigned int* gcnt  = (unsigned int*)((char*)d_ws + 4);
    float*        rnorm = (float*)((char*)d_ws + 16);    // 8192 floats

    rnorm_kernel<<<BB * NN / 4, 256, 0, stream>>>(feat, rnorm, gsum, gcnt);
    scan_kernel<<<BB * BB * NTILES, 256, 0, stream>>>(feat, pts_src, pts_dst,
                                                      rnorm, hptr, wptr, gsum, gcnt);
    finalize_kernel<<<1, 64, 0, stream>>>(gsum, gcnt, out);
}